// Round 4
// baseline (1614.715 us; speedup 1.0000x reference)
//
#include <hip/hip_runtime.h>
#include <cstddef>
#include <cstdint>

#define D_EMB   1408
#define NHEADS  16
#define HD      88
#define BATCH   16
#define SEQ     577
#define M_ROWS  (BATCH * SEQ)   // 9232
#define N_QKV   (3 * D_EMB)     // 4224
#define QKL_N   2816            // qkv-lo row stride (Q|K thirds only)
#define SP      640             // seq padded to 10 x 64 for Vt
#define ATT_SCALE 0.10660035817780521f

#define QT 64
#define KT 64

typedef __attribute__((ext_vector_type(8))) short bf16x8;
typedef __attribute__((ext_vector_type(4))) float f32x4;
typedef unsigned short u16;

static __device__ __forceinline__ u16 f2bf(float x) {
  union { float f; unsigned u; } v; v.f = x;
  unsigned r = v.u + 0x7fff + ((v.u >> 16) & 1);   // RNE
  return (u16)(r >> 16);
}
static __device__ __forceinline__ float bf2f(u16 h) {
  union { unsigned u; float f; } v; v.u = ((unsigned)h) << 16;
  return v.f;
}
static __device__ __forceinline__ void split_hl(float x, u16* hi, u16* lo) {
  u16 h = f2bf(x);
  *hi = h;
  *lo = f2bf(x - bf2f(h));
}

// ---------------------------------------------------------------------------
// split: X fp32 -> H,L bf16
// ---------------------------------------------------------------------------
__global__ __launch_bounds__(256)
void split_kernel(const float* __restrict__ X, u16* __restrict__ H,
                  u16* __restrict__ L, int n4) {
  int i = blockIdx.x * 256 + threadIdx.x;
  if (i >= n4) return;
  float4 v = ((const float4*)X)[i];
  ushort4 h, l;
  split_hl(v.x, &h.x, &l.x);
  split_hl(v.y, &h.y, &l.y);
  split_hl(v.z, &h.z, &l.z);
  split_hl(v.w, &h.w, &l.w);
  ((ushort4*)H)[i] = h;
  ((ushort4*)L)[i] = l;
}

// ---------------------------------------------------------------------------
// transpose+split: W[K][N] fp32 -> Th,Tl[N][K] bf16
// ---------------------------------------------------------------------------
__global__ __launch_bounds__(256)
void transpose_split_kernel(const float* __restrict__ W, u16* __restrict__ Th,
                            u16* __restrict__ Tl, int K, int N) {
  __shared__ float tile[32][33];
  const int n0 = blockIdx.x * 32, k0 = blockIdx.y * 32;
  const int tx = threadIdx.x & 31, ty = threadIdx.x >> 5;
#pragma unroll
  for (int i = 0; i < 4; ++i) {
    int k = ty + i * 8;
    tile[k][tx] = W[(size_t)(k0 + k) * N + n0 + tx];
  }
  __syncthreads();
#pragma unroll
  for (int i = 0; i < 4; ++i) {
    int n = ty + i * 8;
    float v = tile[tx][n];
    u16 h, l;
    split_hl(v, &h, &l);
    Th[(size_t)(n0 + n) * K + k0 + tx] = h;
    Tl[(size_t)(n0 + n) * K + k0 + tx] = l;
  }
}

// ---------------------------------------------------------------------------
// V transpose: qkvH V-third [b*S+s][2816 + h*88 + d] -> vt[bh][d][s]
// vt is [256][96][640] bf16-hi, zero-padded in d(88..95) and s(577..639).
// ---------------------------------------------------------------------------
__global__ __launch_bounds__(256)
void vtrans_kernel(const u16* __restrict__ qkvh, u16* __restrict__ vt) {
  __shared__ u16 tile[64][96];   // [s][d]
  const int st = blockIdx.x, bh = blockIdx.y;
  const int b = bh >> 4, h = bh & 15;
  const int tid = threadIdx.x;
  const int s0 = st * 64;
  for (int idx = tid; idx < 64 * 22; idx += 256) {
    int j = idx / 22, c4 = (idx % 22) * 4;
    int s = s0 + j;
    ushort4 v = make_ushort4(0, 0, 0, 0);
    if (s < SEQ)
      v = *(const ushort4*)(qkvh + (size_t)(b * SEQ + s) * N_QKV + 2 * D_EMB + h * HD + c4);
    *(ushort4*)&tile[j][c4] = v;
  }
  if (tid < 64) {
    bf16x8 z = {0, 0, 0, 0, 0, 0, 0, 0};
    *(bf16x8*)&tile[tid][88] = z;
  }
  __syncthreads();
  for (int idx = tid; idx < 96 * 8; idx += 256) {
    int d = idx >> 3, c8 = (idx & 7) * 8;
    bf16x8 o;
#pragma unroll
    for (int e = 0; e < 8; ++e) o[e] = (short)tile[c8 + e][d];
    *(bf16x8*)(vt + ((size_t)bh * 96 + d) * SP + s0 + c8) = o;
  }
}

// ---------------------------------------------------------------------------
// 3-product hi/lo bf16 MFMA GEMM, NO LDS: fragments loaded global->VGPR.
// Virtual 1-D grid with XCD swizzle: all NX col-blocks of an M-band on 1 XCD.
// 128x128 block, 4 waves 2x2, each wave 64x64 via 4x4 16x16x32 MFMA tiles.
// MODE 0: fp32 out.  MODE 1: hi -> Ch[row*N+col], lo -> Cl[row*2816+col] (col<2816).
// ---------------------------------------------------------------------------
template <int MODE>
__global__ __launch_bounds__(256)
void gemm3p_kernel(const u16* __restrict__ Ah, const u16* __restrict__ Al,
                   const u16* __restrict__ Bh, const u16* __restrict__ Bl,
                   const float* __restrict__ bias,
                   float* __restrict__ Cf, u16* __restrict__ Ch, u16* __restrict__ Cl,
                   int M, int N, int K, int NX) {
  const int lin  = blockIdx.x;
  const int xcd  = lin & 7;
  const int t    = lin >> 3;
  const int band = xcd + 8 * (t / NX);
  const int n    = t % NX;
  const int bm0  = band * 128;
  if (bm0 >= M) return;
  const int bn0  = n * 128;

  const int tid = threadIdx.x, lane = tid & 63, w = tid >> 6;
  const int quad = lane >> 4, lc = lane & 15;
  const int wm = w >> 1, wn = w & 1;

  int offA[4], offB[4];
#pragma unroll
  for (int i = 0; i < 4; ++i) {
    int r = bm0 + wm * 64 + i * 16 + lc;
    if (r > M - 1) r = M - 1;
    offA[i] = r * K;
    offB[i] = (bn0 + wn * 64 + i * 16 + lc) * K;
  }

  f32x4 acc[4][4];
#pragma unroll
  for (int i = 0; i < 4; ++i)
#pragma unroll
    for (int j = 0; j < 4; ++j) acc[i][j] = (f32x4){0.f, 0.f, 0.f, 0.f};

  for (int k0 = 0; k0 < K; k0 += 32) {
    const int ko = k0 + quad * 8;
    bf16x8 ah[4], alo[4], bh[4], blo[4];
#pragma unroll
    for (int i = 0; i < 4; ++i) {
      ah[i]  = *(const bf16x8*)(Ah + offA[i] + ko);
      alo[i] = *(const bf16x8*)(Al + offA[i] + ko);
      bh[i]  = *(const bf16x8*)(Bh + offB[i] + ko);
      blo[i] = *(const bf16x8*)(Bl + offB[i] + ko);
    }
#pragma unroll
    for (int i = 0; i < 4; ++i)
#pragma unroll
      for (int j = 0; j < 4; ++j) {
        acc[i][j] = __builtin_amdgcn_mfma_f32_16x16x32_bf16(ah[i],  bh[j],  acc[i][j], 0, 0, 0);
        acc[i][j] = __builtin_amdgcn_mfma_f32_16x16x32_bf16(ah[i],  blo[j], acc[i][j], 0, 0, 0);
        acc[i][j] = __builtin_amdgcn_mfma_f32_16x16x32_bf16(alo[i], bh[j],  acc[i][j], 0, 0, 0);
      }
  }

#pragma unroll
  for (int j = 0; j < 4; ++j) {
    int col = bn0 + wn * 64 + j * 16 + lc;
    float bj = bias[col];
#pragma unroll
    for (int i = 0; i < 4; ++i) {
#pragma unroll
      for (int rg = 0; rg < 4; ++rg) {
        int row = bm0 + wm * 64 + i * 16 + quad * 4 + rg;
        if (row < M) {
          float v = acc[i][j][rg] + bj;
          if (MODE == 0) {
            Cf[(size_t)row * N + col] = v;
          } else {
            u16 hh, ll;
            split_hl(v, &hh, &ll);
            Ch[(size_t)row * N + col] = hh;
            if (col < QKL_N) Cl[(size_t)row * QKL_N + col] = ll;
          }
        }
      }
    }
  }
}

// ---------------------------------------------------------------------------
// MFMA flash attention v2. Block = (b,h,64-q tile); 4 waves x 16 q-rows.
// Q frags in registers (hi/lo); K staged hi/lo (padded stride 104);
// V from pre-transposed global (bf16-hi only, padded stride 72); KT=64.
// ---------------------------------------------------------------------------
__global__ __launch_bounds__(256)
void attn_kernel2(const u16* __restrict__ qkvh, const u16* __restrict__ qkvl,
                  const u16* __restrict__ vt,
                  u16* __restrict__ outh, u16* __restrict__ outl) {
  __shared__ u16 Khi[KT][104];   // stride 52 words == 20 mod 32 -> 2-way max
  __shared__ u16 Klo[KT][104];
  __shared__ u16 Vs[96][72];     // stride 36 words == 4 mod 32 -> 2-way max
  __shared__ u16 Pb[QT][72];

  const int tid  = threadIdx.x;
  const int lane = tid & 63;
  const int wv   = tid >> 6;
  const int quad = lane >> 4;
  const int lc   = lane & 15;

  const int qt = blockIdx.x, h = blockIdx.y, b = blockIdx.z;
  const int q0 = qt * QT;

  // zero the K pad columns 88..95 once (never re-written by staging)
  if (tid < KT) {
    bf16x8 z = {0, 0, 0, 0, 0, 0, 0, 0};
    *(bf16x8*)&Khi[tid][88] = z;
    *(bf16x8*)&Klo[tid][88] = z;
  }

  // ---- Q fragments in registers: wave's q-row = q0 + wv*16 + lc
  bf16x8 qh[3], ql[3];
  {
    const bf16x8 z = {0, 0, 0, 0, 0, 0, 0, 0};
    int qrow = q0 + wv * 16 + lc;
    bool qv = qrow < SEQ;
    size_t bh_ = (size_t)(b * SEQ + (qv ? qrow : 0));
#pragma unroll
    for (int ks = 0; ks < 3; ++ks) {
      if (!qv || (ks == 2 && quad == 3)) {   // dims 88..95 are past head dim
        qh[ks] = z; ql[ks] = z;
      } else {
        qh[ks] = *(const bf16x8*)(qkvh + bh_ * N_QKV + h * HD + ks * 32 + quad * 8);
        ql[ks] = *(const bf16x8*)(qkvl + bh_ * QKL_N + h * HD + ks * 32 + quad * 8);
      }
    }
  }

  float mrow[4], lrow[4];
#pragma unroll
  for (int r = 0; r < 4; ++r) { mrow[r] = -INFINITY; lrow[r] = 0.f; }
  f32x4 oacc[6];
#pragma unroll
  for (int nn = 0; nn < 6; ++nn) oacc[nn] = (f32x4){0.f, 0.f, 0.f, 0.f};

  const u16* vsrc = vt + (size_t)(b * 16 + h) * 96 * SP;

  for (int kt = 0; kt < SP / KT; ++kt) {   // 10 iterations
    const int k0 = kt * KT;
    __syncthreads();   // prev iter's K/Vs/Pb reads complete

    // ---- stage K hi/lo (64 rows x 88 cols)
    for (int idx = tid; idx < KT * 22; idx += 256) {
      int j = idx / 22, c4 = (idx % 22) * 4;
      int s = k0 + j;
      ushort4 kh = make_ushort4(0, 0, 0, 0), kl = make_ushort4(0, 0, 0, 0);
      if (s < SEQ) {
        size_t rb = (size_t)(b * SEQ + s);
        kh = *(const ushort4*)(qkvh + rb * N_QKV + D_EMB + h * HD + c4);
        kl = *(const ushort4*)(qkvl + rb * QKL_N + D_EMB + h * HD + c4);
      }
      *(ushort4*)&Khi[j][c4] = kh;
      *(ushort4*)&Klo[j][c4] = kl;
    }
    // ---- stage V^T slice (96 rows x 64 cols), contiguous b128 copies
    for (int idx = tid; idx < 96 * 8; idx += 256) {
      int d = idx >> 3, c8 = (idx & 7) * 8;
      *(bf16x8*)&Vs[d][c8] = *(const bf16x8*)(vsrc + (size_t)d * SP + k0 + c8);
    }
    __syncthreads();

    // ---- QK^T: 16 q-rows x 64 keys, 3-product hi/lo
    f32x4 sc[4];
#pragma unroll
    for (int t = 0; t < 4; ++t) {
      f32x4 a = (f32x4){0.f, 0.f, 0.f, 0.f};
#pragma unroll
      for (int ks = 0; ks < 3; ++ks) {
        bf16x8 kh = *(const bf16x8*)&Khi[t * 16 + lc][ks * 32 + quad * 8];
        bf16x8 kl = *(const bf16x8*)&Klo[t * 16 + lc][ks * 32 + quad * 8];
        a = __builtin_amdgcn_mfma_f32_16x16x32_bf16(qh[ks], kh, a, 0, 0, 0);
        a = __builtin_amdgcn_mfma_f32_16x16x32_bf16(qh[ks], kl, a, 0, 0, 0);
        a = __builtin_amdgcn_mfma_f32_16x16x32_bf16(ql[ks], kh, a, 0, 0, 0);
      }
      sc[t] = a;
    }
#pragma unroll
    for (int t = 0; t < 4; ++t) {
      bool valid = (k0 + t * 16 + lc) < SEQ;
#pragma unroll
      for (int r = 0; r < 4; ++r)
        sc[t][r] = valid ? sc[t][r] * ATT_SCALE : -INFINITY;
    }

    // ---- online softmax; row = quad*4+r, reduce across quad's 16 lanes
    float alpha[4];
#pragma unroll
    for (int r = 0; r < 4; ++r) {
      float v = fmaxf(fmaxf(sc[0][r], sc[1][r]), fmaxf(sc[2][r], sc[3][r]));
      v = fmaxf(v, __shfl_xor(v, 1));
      v = fmaxf(v, __shfl_xor(v, 2));
      v = fmaxf(v, __shfl_xor(v, 4));
      v = fmaxf(v, __shfl_xor(v, 8));
      float mnew = fmaxf(mrow[r], v);
      alpha[r] = expf(mrow[r] - mnew);
      mrow[r] = mnew;
      float s = 0.f;
#pragma unroll
      for (int t = 0; t < 4; ++t) {
        float p = expf(sc[t][r] - mnew);
        sc[t][r] = p;
        s += p;
      }
      s += __shfl_xor(s, 1);
      s += __shfl_xor(s, 2);
      s += __shfl_xor(s, 4);
      s += __shfl_xor(s, 8);
      lrow[r] = lrow[r] * alpha[r] + s;
    }
#pragma unroll
    for (int t = 0; t < 4; ++t)
#pragma unroll
      for (int r = 0; r < 4; ++r)
        Pb[wv * 16 + quad * 4 + r][t * 16 + lc] = f2bf(sc[t][r]);
#pragma unroll
    for (int nn = 0; nn < 6; ++nn)
#pragma unroll
      for (int r = 0; r < 4; ++r) oacc[nn][r] *= alpha[r];
    __syncthreads();   // Pb visible

    // ---- PV: O[16x96] += P[16x64] @ V[64x96]
    bf16x8 p0 = *(const bf16x8*)&Pb[wv * 16 + lc][quad * 8];
    bf16x8 p1 = *(const bf16x8*)&Pb[wv * 16 + lc][32 + quad * 8];
#pragma unroll
    for (int nn = 0; nn < 6; ++nn) {
      bf16x8 v0 = *(const bf16x8*)&Vs[nn * 16 + lc][quad * 8];
      bf16x8 v1 = *(const bf16x8*)&Vs[nn * 16 + lc][32 + quad * 8];
      oacc[nn] = __builtin_amdgcn_mfma_f32_16x16x32_bf16(p0, v0, oacc[nn], 0, 0, 0);
      oacc[nn] = __builtin_amdgcn_mfma_f32_16x16x32_bf16(p1, v1, oacc[nn], 0, 0, 0);
    }
  }

  // ---- normalize + split-store
#pragma unroll
  for (int r = 0; r < 4; ++r) {
    int s = q0 + wv * 16 + quad * 4 + r;
    if (s < SEQ) {
      float inv = 1.f / lrow[r];
      size_t base = (size_t)(b * SEQ + s) * D_EMB + h * HD;
#pragma unroll
      for (int nn = 0; nn < 6; ++nn) {
        int d = nn * 16 + lc;
        if (d < HD) {
          float v = oacc[nn][r] * inv;
          u16 hh, ll;
          split_hl(v, &hh, &ll);
          outh[base + d] = hh;
          outl[base + d] = ll;
        }
      }
    }
  }
}

// ---------------------------------------------------------------------------
extern "C" void kernel_launch(void* const* d_in, const int* in_sizes, int n_in,
                              void* d_out, int out_size, void* d_ws, size_t ws_size,
                              hipStream_t stream) {
  const float* hs    = (const float*)d_in[0];
  const float* wqkv  = (const float*)d_in[1];
  const float* bqkv  = (const float*)d_in[2];
  const float* wproj = (const float*)d_in[3];
  const float* bproj = (const float*)d_in[4];
  float* out = (float*)d_out;

  // workspace (u16 elements):
  //  qkvH [9232][4224]; qkvL [9232][2816] (Q|K lo only);
  //  hsH/hsL [9232][1408] each  (aliased by attnH/attnL after GEMM1);
  //  vt [256][96][640]          (aliased by wtH/wtL outside attention phase)
  u16* qkvH = (u16*)d_ws;
  u16* qkvL = qkvH + (size_t)M_ROWS * N_QKV;
  u16* hsH  = qkvL + (size_t)M_ROWS * QKL_N;
  u16* hsL  = hsH + (size_t)M_ROWS * D_EMB;
  u16* vt   = hsL + (size_t)M_ROWS * D_EMB;
  u16* wtH  = vt;                                   // alias (disjoint lifetime)
  u16* wtL  = wtH + (size_t)N_QKV * D_EMB;
  u16* attnH = hsH;                                 // alias (hs dead after GEMM1)
  u16* attnL = hsL;

  // 1) split hidden_states
  {
    int n4 = (M_ROWS * D_EMB) / 4;
    split_kernel<<<(n4 + 255) / 256, 256, 0, stream>>>(hs, hsH, hsL, n4);
  }
  // 2) transpose+split w_qkv -> wt (in vt region)
  {
    dim3 g(N_QKV / 32, D_EMB / 32);
    transpose_split_kernel<<<g, 256, 0, stream>>>(wqkv, wtH, wtL, D_EMB, N_QKV);
  }
  // 3) QKV GEMM (no-LDS, XCD-swizzled): 33 cols x 80 padded bands
  {
    gemm3p_kernel<1><<<33 * 80, 256, 0, stream>>>(hsH, hsL, wtH, wtL, bqkv,
                                                  nullptr, qkvH, qkvL,
                                                  M_ROWS, N_QKV, D_EMB, 33);
  }
  // 4) V transpose (wt dead; vt region reused)
  {
    dim3 g(SP / 64, BATCH * NHEADS);
    vtrans_kernel<<<g, 256, 0, stream>>>(qkvH, vt);
  }
  // 5) attention
  {
    dim3 g(SP / QT, NHEADS, BATCH);
    attn_kernel2<<<g, 256, 0, stream>>>(qkvH, qkvL, vt, attnH, attnL);
  }
  // 6) transpose+split w_proj -> wt (vt dead)
  {
    dim3 g(D_EMB / 32, D_EMB / 32);
    transpose_split_kernel<<<g, 256, 0, stream>>>(wproj, wtH, wtL, D_EMB, D_EMB);
  }
  // 7) output projection: 11 cols x 80 padded bands
  {
    gemm3p_kernel<0><<<11 * 80, 256, 0, stream>>>(attnH, attnL, wtH, wtL, bproj,
                                                  out, nullptr, nullptr,
                                                  M_ROWS, D_EMB, D_EMB, 11);
  }
}

// Round 5
// 922.076 us; speedup vs baseline: 1.7512x; 1.7512x over previous
//
#include <hip/hip_runtime.h>
#include <cstddef>
#include <cstdint>

#define D_EMB   1408
#define NHEADS  16
#define HD      88
#define BATCH   16
#define SEQ     577
#define M_ROWS  (BATCH * SEQ)   // 9232
#define N_QKV   (3 * D_EMB)     // 4224
#define QKL_N   2816            // qkv-lo row stride (Q|K thirds only)
#define SP      640             // seq padded to 10 x 64 for Vt
#define ATT_SCALE 0.10660035817780521f

#define QT 64
#define KT 64

typedef __attribute__((ext_vector_type(8))) short bf16x8;
typedef __attribute__((ext_vector_type(4))) float f32x4;
typedef unsigned short u16;

static __device__ __forceinline__ u16 f2bf(float x) {
  union { float f; unsigned u; } v; v.f = x;
  unsigned r = v.u + 0x7fff + ((v.u >> 16) & 1);   // RNE
  return (u16)(r >> 16);
}
static __device__ __forceinline__ float bf2f(u16 h) {
  union { unsigned u; float f; } v; v.u = ((unsigned)h) << 16;
  return v.f;
}
static __device__ __forceinline__ void split_hl(float x, u16* hi, u16* lo) {
  u16 h = f2bf(x);
  *hi = h;
  *lo = f2bf(x - bf2f(h));
}

// async global->LDS, 16 B per lane; lds dest = wave-uniform base + lane*16
static __device__ __forceinline__ void async16(const u16* g, u16* l) {
  __builtin_amdgcn_global_load_lds(
      (const __attribute__((address_space(1))) unsigned int*)g,
      (__attribute__((address_space(3))) unsigned int*)l, 16, 0, 0);
}

// ---------------------------------------------------------------------------
// split: X fp32 -> H,L bf16
// ---------------------------------------------------------------------------
__global__ __launch_bounds__(256)
void split_kernel(const float* __restrict__ X, u16* __restrict__ H,
                  u16* __restrict__ L, int n4) {
  int i = blockIdx.x * 256 + threadIdx.x;
  if (i >= n4) return;
  float4 v = ((const float4*)X)[i];
  ushort4 h, l;
  split_hl(v.x, &h.x, &l.x);
  split_hl(v.y, &h.y, &l.y);
  split_hl(v.z, &h.z, &l.z);
  split_hl(v.w, &h.w, &l.w);
  ((ushort4*)H)[i] = h;
  ((ushort4*)L)[i] = l;
}

// ---------------------------------------------------------------------------
// transpose+split: W[K][N] fp32 -> Th,Tl[N][K] bf16
// ---------------------------------------------------------------------------
__global__ __launch_bounds__(256)
void transpose_split_kernel(const float* __restrict__ W, u16* __restrict__ Th,
                            u16* __restrict__ Tl, int K, int N) {
  __shared__ float tile[32][33];
  const int n0 = blockIdx.x * 32, k0 = blockIdx.y * 32;
  const int tx = threadIdx.x & 31, ty = threadIdx.x >> 5;
#pragma unroll
  for (int i = 0; i < 4; ++i) {
    int k = ty + i * 8;
    tile[k][tx] = W[(size_t)(k0 + k) * N + n0 + tx];
  }
  __syncthreads();
#pragma unroll
  for (int i = 0; i < 4; ++i) {
    int n = ty + i * 8;
    float v = tile[tx][n];
    u16 h, l;
    split_hl(v, &h, &l);
    Th[(size_t)(n0 + n) * K + k0 + tx] = h;
    Tl[(size_t)(n0 + n) * K + k0 + tx] = l;
  }
}

// ---------------------------------------------------------------------------
// V transpose: qkvH V-third -> vt[bh][d][s], [256][96][640], zero-padded.
// ---------------------------------------------------------------------------
__global__ __launch_bounds__(256)
void vtrans_kernel(const u16* __restrict__ qkvh, u16* __restrict__ vt) {
  __shared__ u16 tile[64][96];   // [s][d]
  const int st = blockIdx.x, bh = blockIdx.y;
  const int b = bh >> 4, h = bh & 15;
  const int tid = threadIdx.x;
  const int s0 = st * 64;
  for (int idx = tid; idx < 64 * 22; idx += 256) {
    int j = idx / 22, c4 = (idx % 22) * 4;
    int s = s0 + j;
    ushort4 v = make_ushort4(0, 0, 0, 0);
    if (s < SEQ)
      v = *(const ushort4*)(qkvh + (size_t)(b * SEQ + s) * N_QKV + 2 * D_EMB + h * HD + c4);
    *(ushort4*)&tile[j][c4] = v;
  }
  if (tid < 64) {
    bf16x8 z = {0, 0, 0, 0, 0, 0, 0, 0};
    *(bf16x8*)&tile[tid][88] = z;
  }
  __syncthreads();
  for (int idx = tid; idx < 96 * 8; idx += 256) {
    int d = idx >> 3, c8 = (idx & 7) * 8;
    bf16x8 o;
#pragma unroll
    for (int e = 0; e < 8; ++e) o[e] = (short)tile[c8 + e][d];
    *(bf16x8*)(vt + ((size_t)bh * 96 + d) * SP + s0 + c8) = o;
  }
}

// ---------------------------------------------------------------------------
// 3-product hi/lo bf16 MFMA GEMM, LDS-staged (global_load_lds w16), with
// XCD-swizzled 1-D grid: band = (lin&7) + 8*(t/NX), n = t%NX -> all NX
// column-blocks of an M-band execute on one XCD (A-band hot in its L2).
// 128x128 tile, BK=32, 4 waves 2x2, 64x64/wave via 4x4 16x16x32 MFMA.
// LDS 16B-blocks XOR-swizzled: phys qp holds logical q = qp ^ (row&3).
// MODE 0: fp32 out.  MODE 1: hi -> Ch[row*N+col]; lo -> Cl[row*2816+col].
// ---------------------------------------------------------------------------
template <int MODE>
__global__ __launch_bounds__(256)
void gemm3p_kernel(const u16* __restrict__ Ah, const u16* __restrict__ Al,
                   const u16* __restrict__ Bh, const u16* __restrict__ Bl,
                   const float* __restrict__ bias,
                   float* __restrict__ Cf, u16* __restrict__ Ch, u16* __restrict__ Cl,
                   int M, int N, int K, int NX) {
  const int lin  = blockIdx.x;
  const int xcd  = lin & 7;
  const int t    = lin >> 3;
  const int band = xcd + 8 * (t / NX);
  const int nblk = t % NX;
  const int bm0  = band * 128;
  if (bm0 >= M) return;
  const int bn0  = nblk * 128;

  __shared__ u16 sA[2][128 * 32];
  __shared__ u16 sB[2][128 * 32];
  const int tid  = threadIdx.x;
  const int lane = tid & 63;
  const int w    = tid >> 6;
  const int quad = lane >> 4, lc = lane & 15;
  const int wm = w >> 1, wn = w & 1;

  f32x4 acc[4][4];
#pragma unroll
  for (int i = 0; i < 4; ++i)
#pragma unroll
    for (int j = 0; j < 4; ++j) acc[i][j] = (f32x4){0.f, 0.f, 0.f, 0.f};

  for (int k0 = 0; k0 < K; k0 += 32) {
    __syncthreads();   // prior-iter LDS reads complete before restage
#pragma unroll
    for (int i = 0; i < 2; ++i) {
      int e0  = w * 1024 + i * 512 + lane * 8;   // element idx of lane's 16B block
      int r   = e0 >> 5;
      int qp  = (e0 >> 3) & 3;
      int qlg = qp ^ (r & 3);
      int ra  = bm0 + r; if (ra > M - 1) ra = M - 1;
      size_t ga = (size_t)ra * K + (k0 + qlg * 8);
      async16(Ah + ga, &sA[0][w * 1024 + i * 512]);
      async16(Al + ga, &sA[1][w * 1024 + i * 512]);
      size_t gb = (size_t)(bn0 + r) * K + (k0 + qlg * 8);
      async16(Bh + gb, &sB[0][w * 1024 + i * 512]);
      async16(Bl + gb, &sB[1][w * 1024 + i * 512]);
    }
    __syncthreads();   // drains vmcnt (global_load_lds) per barrier semantics

    bf16x8 fah[4], fal[4], fbh[4], fbl[4];
    const int qp = quad ^ (lc & 3);
#pragma unroll
    for (int i = 0; i < 4; ++i) {
      int rowa = wm * 64 + i * 16 + lc;
      fah[i] = *(const bf16x8*)&sA[0][rowa * 32 + qp * 8];
      fal[i] = *(const bf16x8*)&sA[1][rowa * 32 + qp * 8];
      int rowb = wn * 64 + i * 16 + lc;
      fbh[i] = *(const bf16x8*)&sB[0][rowb * 32 + qp * 8];
      fbl[i] = *(const bf16x8*)&sB[1][rowb * 32 + qp * 8];
    }
#pragma unroll
    for (int i = 0; i < 4; ++i)
#pragma unroll
      for (int j = 0; j < 4; ++j) {
        acc[i][j] = __builtin_amdgcn_mfma_f32_16x16x32_bf16(fah[i], fbh[j], acc[i][j], 0, 0, 0);
        acc[i][j] = __builtin_amdgcn_mfma_f32_16x16x32_bf16(fah[i], fbl[j], acc[i][j], 0, 0, 0);
        acc[i][j] = __builtin_amdgcn_mfma_f32_16x16x32_bf16(fal[i], fbh[j], acc[i][j], 0, 0, 0);
      }
  }

  // epilogue: C/D layout col=lc, row=quad*4+reg
#pragma unroll
  for (int j = 0; j < 4; ++j) {
    int col = bn0 + wn * 64 + j * 16 + lc;
    float bj = bias[col];
#pragma unroll
    for (int i = 0; i < 4; ++i) {
#pragma unroll
      for (int rg = 0; rg < 4; ++rg) {
        int row = bm0 + wm * 64 + i * 16 + quad * 4 + rg;
        if (row < M) {
          float v = acc[i][j][rg] + bj;
          if (MODE == 0) {
            Cf[(size_t)row * N + col] = v;
          } else {
            u16 hh, ll;
            split_hl(v, &hh, &ll);
            Ch[(size_t)row * N + col] = hh;
            if (col < QKL_N) Cl[(size_t)row * QKL_N + col] = ll;
          }
        }
      }
    }
  }
}

// ---------------------------------------------------------------------------
// MFMA flash attention v2 (round-4, kept). Block = (b,h,64-q tile).
// ---------------------------------------------------------------------------
__global__ __launch_bounds__(256)
void attn_kernel2(const u16* __restrict__ qkvh, const u16* __restrict__ qkvl,
                  const u16* __restrict__ vt,
                  u16* __restrict__ outh, u16* __restrict__ outl) {
  __shared__ u16 Khi[KT][104];   // stride 52 words == 20 mod 32 -> <=2-way
  __shared__ u16 Klo[KT][104];
  __shared__ u16 Vs[96][72];     // stride 36 words == 4 mod 32 -> <=2-way
  __shared__ u16 Pb[QT][72];

  const int tid  = threadIdx.x;
  const int lane = tid & 63;
  const int wv   = tid >> 6;
  const int quad = lane >> 4;
  const int lc   = lane & 15;

  const int qt = blockIdx.x, h = blockIdx.y, b = blockIdx.z;
  const int q0 = qt * QT;

  if (tid < KT) {
    bf16x8 z = {0, 0, 0, 0, 0, 0, 0, 0};
    *(bf16x8*)&Khi[tid][88] = z;
    *(bf16x8*)&Klo[tid][88] = z;
  }

  bf16x8 qh[3], ql[3];
  {
    const bf16x8 z = {0, 0, 0, 0, 0, 0, 0, 0};
    int qrow = q0 + wv * 16 + lc;
    bool qv = qrow < SEQ;
    size_t bh_ = (size_t)(b * SEQ + (qv ? qrow : 0));
#pragma unroll
    for (int ks = 0; ks < 3; ++ks) {
      if (!qv || (ks == 2 && quad == 3)) {
        qh[ks] = z; ql[ks] = z;
      } else {
        qh[ks] = *(const bf16x8*)(qkvh + bh_ * N_QKV + h * HD + ks * 32 + quad * 8);
        ql[ks] = *(const bf16x8*)(qkvl + bh_ * QKL_N + h * HD + ks * 32 + quad * 8);
      }
    }
  }

  float mrow[4], lrow[4];
#pragma unroll
  for (int r = 0; r < 4; ++r) { mrow[r] = -INFINITY; lrow[r] = 0.f; }
  f32x4 oacc[6];
#pragma unroll
  for (int nn = 0; nn < 6; ++nn) oacc[nn] = (f32x4){0.f, 0.f, 0.f, 0.f};

  const u16* vsrc = vt + (size_t)(b * 16 + h) * 96 * SP;

  for (int kt = 0; kt < SP / KT; ++kt) {
    const int k0 = kt * KT;
    __syncthreads();

    for (int idx = tid; idx < KT * 22; idx += 256) {
      int j = idx / 22, c4 = (idx % 22) * 4;
      int s = k0 + j;
      ushort4 kh = make_ushort4(0, 0, 0, 0), kl = make_ushort4(0, 0, 0, 0);
      if (s < SEQ) {
        size_t rb = (size_t)(b * SEQ + s);
        kh = *(const ushort4*)(qkvh + rb * N_QKV + D_EMB + h * HD + c4);
        kl = *(const ushort4*)(qkvl + rb * QKL_N + D_EMB + h * HD + c4);
      }
      *(ushort4*)&Khi[j][c4] = kh;
      *(ushort4*)&Klo[j][c4] = kl;
    }
    for (int idx = tid; idx < 96 * 8; idx += 256) {
      int d = idx >> 3, c8 = (idx & 7) * 8;
      *(bf16x8*)&Vs[d][c8] = *(const bf16x8*)(vsrc + (size_t)d * SP + k0 + c8);
    }
    __syncthreads();

    f32x4 sc[4];
#pragma unroll
    for (int t = 0; t < 4; ++t) {
      f32x4 a = (f32x4){0.f, 0.f, 0.f, 0.f};
#pragma unroll
      for (int ks = 0; ks < 3; ++ks) {
        bf16x8 kh = *(const bf16x8*)&Khi[t * 16 + lc][ks * 32 + quad * 8];
        bf16x8 kl = *(const bf16x8*)&Klo[t * 16 + lc][ks * 32 + quad * 8];
        a = __builtin_amdgcn_mfma_f32_16x16x32_bf16(qh[ks], kh, a, 0, 0, 0);
        a = __builtin_amdgcn_mfma_f32_16x16x32_bf16(qh[ks], kl, a, 0, 0, 0);
        a = __builtin_amdgcn_mfma_f32_16x16x32_bf16(ql[ks], kh, a, 0, 0, 0);
      }
      sc[t] = a;
    }
#pragma unroll
    for (int t = 0; t < 4; ++t) {
      bool valid = (k0 + t * 16 + lc) < SEQ;
#pragma unroll
      for (int r = 0; r < 4; ++r)
        sc[t][r] = valid ? sc[t][r] * ATT_SCALE : -INFINITY;
    }

    float alpha[4];
#pragma unroll
    for (int r = 0; r < 4; ++r) {
      float v = fmaxf(fmaxf(sc[0][r], sc[1][r]), fmaxf(sc[2][r], sc[3][r]));
      v = fmaxf(v, __shfl_xor(v, 1));
      v = fmaxf(v, __shfl_xor(v, 2));
      v = fmaxf(v, __shfl_xor(v, 4));
      v = fmaxf(v, __shfl_xor(v, 8));
      float mnew = fmaxf(mrow[r], v);
      alpha[r] = expf(mrow[r] - mnew);
      mrow[r] = mnew;
      float s = 0.f;
#pragma unroll
      for (int t = 0; t < 4; ++t) {
        float p = expf(sc[t][r] - mnew);
        sc[t][r] = p;
        s += p;
      }
      s += __shfl_xor(s, 1);
      s += __shfl_xor(s, 2);
      s += __shfl_xor(s, 4);
      s += __shfl_xor(s, 8);
      lrow[r] = lrow[r] * alpha[r] + s;
    }
#pragma unroll
    for (int t = 0; t < 4; ++t)
#pragma unroll
      for (int r = 0; r < 4; ++r)
        Pb[wv * 16 + quad * 4 + r][t * 16 + lc] = f2bf(sc[t][r]);
#pragma unroll
    for (int nn = 0; nn < 6; ++nn)
#pragma unroll
      for (int r = 0; r < 4; ++r) oacc[nn][r] *= alpha[r];
    __syncthreads();

    bf16x8 p0 = *(const bf16x8*)&Pb[wv * 16 + lc][quad * 8];
    bf16x8 p1 = *(const bf16x8*)&Pb[wv * 16 + lc][32 + quad * 8];
#pragma unroll
    for (int nn = 0; nn < 6; ++nn) {
      bf16x8 v0 = *(const bf16x8*)&Vs[nn * 16 + lc][quad * 8];
      bf16x8 v1 = *(const bf16x8*)&Vs[nn * 16 + lc][32 + quad * 8];
      oacc[nn] = __builtin_amdgcn_mfma_f32_16x16x32_bf16(p0, v0, oacc[nn], 0, 0, 0);
      oacc[nn] = __builtin_amdgcn_mfma_f32_16x16x32_bf16(p1, v1, oacc[nn], 0, 0, 0);
    }
  }

#pragma unroll
  for (int r = 0; r < 4; ++r) {
    int s = q0 + wv * 16 + quad * 4 + r;
    if (s < SEQ) {
      float inv = 1.f / lrow[r];
      size_t base = (size_t)(b * SEQ + s) * D_EMB + h * HD;
#pragma unroll
      for (int nn = 0; nn < 6; ++nn) {
        int d = nn * 16 + lc;
        if (d < HD) {
          float v = oacc[nn][r] * inv;
          u16 hh, ll;
          split_hl(v, &hh, &ll);
          outh[base + d] = hh;
          outl[base + d] = ll;
        }
      }
    }
  }
}

// ---------------------------------------------------------------------------
extern "C" void kernel_launch(void* const* d_in, const int* in_sizes, int n_in,
                              void* d_out, int out_size, void* d_ws, size_t ws_size,
                              hipStream_t stream) {
  const float* hs    = (const float*)d_in[0];
  const float* wqkv  = (const float*)d_in[1];
  const float* bqkv  = (const float*)d_in[2];
  const float* wproj = (const float*)d_in[3];
  const float* bproj = (const float*)d_in[4];
  float* out = (float*)d_out;

  u16* qkvH = (u16*)d_ws;
  u16* qkvL = qkvH + (size_t)M_ROWS * N_QKV;
  u16* hsH  = qkvL + (size_t)M_ROWS * QKL_N;
  u16* hsL  = hsH + (size_t)M_ROWS * D_EMB;
  u16* vt   = hsL + (size_t)M_ROWS * D_EMB;
  u16* wtH  = vt;                                   // alias (disjoint lifetime)
  u16* wtL  = wtH + (size_t)N_QKV * D_EMB;
  u16* attnH = hsH;                                 // alias (hs dead after GEMM1)
  u16* attnL = hsL;

  // 1) split hidden_states
  {
    int n4 = (M_ROWS * D_EMB) / 4;
    split_kernel<<<(n4 + 255) / 256, 256, 0, stream>>>(hs, hsH, hsL, n4);
  }
  // 2) transpose+split w_qkv -> wt (in vt region)
  {
    dim3 g(N_QKV / 32, D_EMB / 32);
    transpose_split_kernel<<<g, 256, 0, stream>>>(wqkv, wtH, wtL, D_EMB, N_QKV);
  }
  // 3) QKV GEMM (LDS-staged + XCD swizzle): 33 cols x 80 padded bands
  {
    gemm3p_kernel<1><<<33 * 80, 256, 0, stream>>>(hsH, hsL, wtH, wtL, bqkv,
                                                  nullptr, qkvH, qkvL,
                                                  M_ROWS, N_QKV, D_EMB, 33);
  }
  // 4) V transpose (wt dead; vt region reused)
  {
    dim3 g(SP / 64, BATCH * NHEADS);
    vtrans_kernel<<<g, 256, 0, stream>>>(qkvH, vt);
  }
  // 5) attention
  {
    dim3 g(SP / QT, NHEADS, BATCH);
    attn_kernel2<<<g, 256, 0, stream>>>(qkvH, qkvL, vt, attnH, attnL);
  }
  // 6) transpose+split w_proj -> wt (vt dead)
  {
    dim3 g(D_EMB / 32, D_EMB / 32);
    transpose_split_kernel<<<g, 256, 0, stream>>>(wproj, wtH, wtL, D_EMB, D_EMB);
  }
  // 7) output projection: 11 cols x 80 padded bands
  {
    gemm3p_kernel<0><<<11 * 80, 256, 0, stream>>>(attnH, attnL, wtH, wtL, bproj,
                                                  out, nullptr, nullptr,
                                                  M_ROWS, D_EMB, D_EMB, 11);
  }
}